// Round 10
// baseline (189.533 us; speedup 1.0000x reference)
//
#include <hip/hip_runtime.h>
#include <hip/hip_bf16.h>
#include <stdint.h>

#define HEADS 8
#define DHEAD 64
#define BATCH 4
#define SEQ   8192
#define DIM   256
#define INNER 512
#define QKVC  1536
#define ROWS  32768   // BATCH*SEQ
#define EPS   1e-5f

typedef unsigned short u16;
typedef unsigned long long u64;
typedef __attribute__((ext_vector_type(8))) short bf16x8;
typedef __attribute__((ext_vector_type(4))) float f32x4;

#define AS1 __attribute__((address_space(1)))
#define AS3 __attribute__((address_space(3)))

__device__ __forceinline__ void async16(const void* g, void* l) {
  __builtin_amdgcn_global_load_lds((AS1 unsigned int*)g, (AS3 unsigned int*)l, 16, 0, 0);
}

__device__ __forceinline__ float bf2f(u16 u) {
  union { uint32_t i; float f; } v; v.i = ((uint32_t)u) << 16; return v.f;
}
__device__ __forceinline__ u16 f2bf(float f) {
  union { float f; uint32_t i; } v; v.f = f;
  uint32_t x = v.i;
  return (u16)((x + 0x7fffu + ((x >> 16) & 1u)) >> 16);  // RNE
}

// ---------------- prep (unchanged) ----------------
__global__ __launch_bounds__(256) void prep(const float* __restrict__ x,
                                            const float* __restrict__ w,
                                            u16* __restrict__ xb,
                                            u16* __restrict__ wqB,
                                            u16* __restrict__ wkvP,
                                            float* __restrict__ dots) {
  int bid = blockIdx.x;
  if (bid < 8192) {
    int i = (bid * 256 + threadIdx.x) * 4;
    float4 v = *(const float4*)(x + i);
    ushort4 o; o.x = f2bf(v.x); o.y = f2bf(v.y); o.z = f2bf(v.z); o.w = f2bf(v.w);
    *(ushort4*)(xb + i) = o;
  } else if (bid < 8704) {
    int id = (bid - 8192) * 256 + threadIdx.x;
    int k = id >> 9, j = id & 511;
    wqB[id] = f2bf(w[k * QKVC + j]);            // Wq row-major [256 k][512 j]
  } else if (bid < 9728) {
    int id = (bid - 8704) * 256 + threadIdx.x;  // 0..262143
    int j    = id & 7;
    int lane = (id >> 3) & 63;
    int frag = (id >> 9) & 63;                  // 64 fragments
    int h    = id >> 15;                        // 8 heads
    int fn   = frag & 3;
    int half = (frag >> 2) & 1;
    int ks   = (frag >> 3) & 1;
    int kk   = frag >> 4;
    int col  = half * 64 + fn * 16 + (lane & 15);
    int kidx = kk * 64 + ks * 32 + (lane >> 4) * 8 + j;
    int oc   = (col < 64) ? (512 + h * 64 + col) : (1024 + h * 64 + (col - 64));
    wkvP[id] = f2bf(w[kidx * QKVC + oc]);
  } else {
    int i = ((bid - 9728) * 256 + threadIdx.x) * 4;
    float4 z; z.x = 0.f; z.y = 0.f; z.z = 0.f; z.w = 0.f;
    *(float4*)(dots + i) = z;
  }
}

// ---------------- gemm_tile (used by make_G only) ----------------
__device__ __forceinline__ void gemm_tile(const u16* __restrict__ A, int lda,
                                          const u16* __restrict__ Bt, int ldb,
                                          int K, int row0, int col0,
                                          u16* sA, u16* sB, f32x4 acc[4][4]) {
  const int tid = threadIdx.x, lane = tid & 63, wave = tid >> 6;
  const int m = lane & 15, q = lane >> 4;
  const int mr = (wave >> 1) * 64, nc = (wave & 1) * 64;
  for (int kk = 0; kk < K; kk += 64) {
#pragma unroll
    for (int it = 0; it < 4; ++it) {
      int c = it * 256 + tid;
      int r = c >> 3, kc = (c ^ r) & 7;
      async16(A + (size_t)(row0 + r) * lda + kk + kc * 8, sA + (it * 256 + wave * 64) * 8);
      async16(Bt + (size_t)(col0 + r) * ldb + kk + kc * 8, sB + (it * 256 + wave * 64) * 8);
    }
    __syncthreads();
#pragma unroll
    for (int ks = 0; ks < 2; ++ks) {
      bf16x8 af[4], bfr[4];
#pragma unroll
      for (int f = 0; f < 4; ++f) {
        int ra = mr + f * 16 + m;
        int rb = nc + f * 16 + m;
        af[f]  = *(const bf16x8*)&sA[ra * 64 + (((ks * 4 + q) ^ (m & 7)) * 8)];
        bfr[f] = *(const bf16x8*)&sB[rb * 64 + (((ks * 4 + q) ^ (m & 7)) * 8)];
      }
#pragma unroll
      for (int fm = 0; fm < 4; ++fm)
#pragma unroll
        for (int fn = 0; fn < 4; ++fn)
          acc[fm][fn] = __builtin_amdgcn_mfma_f32_16x16x32_bf16(af[fm], bfr[fn], acc[fm][fn], 0, 0, 0);
    }
    __syncthreads();
  }
}

// ---------------- GEMM-KV + instance norm + dots — BARRIER-FREE K-loop ----------------
// grid (128 row-groups of 256 tokens, 8 heads) = 1024 blocks, 2 tiles/block.
// A and B fragments both loaded straight from global (L2-hot: all 8 head-blocks
// of a row-group share an XCD under round-robin id%8) -> NO LDS, NO barriers in
// the K-loop; compiler emits fine-grained vmcnt pipelining (AITER pattern).
// LDS only holds knT/vnT for the norm->dots transpose (2 barriers per tile).
__global__ __launch_bounds__(256, 2) void gemm_kv_dots(const u16* __restrict__ A,
                                                       const u16* __restrict__ wkvP,
                                                       float* __restrict__ dots) {
  __shared__ alignas(16) u16 smem[17408];  // 34816 B: knT + vnT only
  u16* knT = smem;            // [64 d][136 tok]
  u16* vnT = smem + 8704;

  const int tid = threadIdx.x, lane = tid & 63, wave = tid >> 6;
  const int m = lane & 15, q = lane >> 4;
  const int h = blockIdx.y;
  const int half = wave & 1;              // 0 = k cols, 1 = v cols
  const int rowbase = (wave >> 1) * 64;
  const u16* bp = wkvP + (size_t)h * 32768 + lane * 8;

  f32x4 dacc[4];
#pragma unroll
  for (int f = 0; f < 4; ++f) dacc[f] = (f32x4){0.f, 0.f, 0.f, 0.f};

  for (int t = 0; t < 2; ++t) {
    const int row0 = (blockIdx.x * 2 + t) * 128;
    const u16* ab = A + (size_t)(row0 + rowbase + m) * DIM + q * 8;

    f32x4 acc[4][4];
#pragma unroll
    for (int i = 0; i < 4; ++i)
#pragma unroll
      for (int j = 0; j < 4; ++j) acc[i][j] = (f32x4){0.f, 0.f, 0.f, 0.f};

#pragma unroll
    for (int kx = 0; kx < 8; ++kx) {      // kx = k-step of 32
      const int fb = (kx * 2 + half) * 4;
      bf16x8 bfr[4], af[4];
#pragma unroll
      for (int fn = 0; fn < 4; ++fn)
        bfr[fn] = *(const bf16x8*)(bp + (size_t)(fb + fn) * 512);
#pragma unroll
      for (int f = 0; f < 4; ++f)
        af[f] = *(const bf16x8*)(ab + (size_t)(f * 16) * DIM + kx * 32);
#pragma unroll
      for (int fm = 0; fm < 4; ++fm)
#pragma unroll
        for (int fn = 0; fn < 4; ++fn)
          acc[fm][fn] = __builtin_amdgcn_mfma_f32_16x16x32_bf16(af[fm], bfr[fn], acc[fm][fn], 0, 0, 0);
    }

    // instance norm: shfl butterfly over lane&15, write transposed bf16
    u16* dst = half ? vnT : knT;
#pragma unroll
    for (int fm = 0; fm < 4; ++fm) {
      f32x4 s  = acc[fm][0] + acc[fm][1] + acc[fm][2] + acc[fm][3];
      f32x4 s2 = (f32x4){0.f, 0.f, 0.f, 0.f};
#pragma unroll
      for (int fn = 0; fn < 4; ++fn)
#pragma unroll
        for (int r = 0; r < 4; ++r) s2[r] = fmaf(acc[fm][fn][r], acc[fm][fn][r], s2[r]);
#pragma unroll
      for (int mask = 1; mask <= 8; mask <<= 1) {
#pragma unroll
        for (int r = 0; r < 4; ++r) {
          s[r]  += __shfl_xor(s[r],  mask, 64);
          s2[r] += __shfl_xor(s2[r], mask, 64);
        }
      }
      f32x4 mu, rs;
#pragma unroll
      for (int r = 0; r < 4; ++r) {
        mu[r] = s[r] * (1.f / 64.f);
        float var = s2[r] * (1.f / 64.f) - mu[r] * mu[r];
        rs[r] = rsqrtf(var + EPS);
      }
      const int tokb = rowbase + fm * 16 + q * 4;
#pragma unroll
      for (int fn = 0; fn < 4; ++fn) {
        int d = fn * 16 + m;
        u64 pk = 0;
#pragma unroll
        for (int r = 0; r < 4; ++r) {
          u16 hv = f2bf((acc[fm][fn][r] - mu[r]) * rs[r]);
          pk |= (u64)hv << (16 * r);
        }
        *(u64*)(dst + d * 136 + tokb) = pk;   // 8B-aligned; 2-way bank alias (free)
      }
    }
    __syncthreads();

    // dots accumulate: dacc[d][e] += sum_tok knT[d][tok]*vnT[e][tok] (K=128)
#pragma unroll
    for (int ks = 0; ks < 4; ++ks) {
      bf16x8 a = *(const bf16x8*)&knT[(wave * 16 + m) * 136 + ks * 32 + q * 8];
#pragma unroll
      for (int fn = 0; fn < 4; ++fn) {
        bf16x8 bb = *(const bf16x8*)&vnT[(fn * 16 + m) * 136 + ks * 32 + q * 8];
        dacc[fn] = __builtin_amdgcn_mfma_f32_16x16x32_bf16(a, bb, dacc[fn], 0, 0, 0);
      }
    }
    __syncthreads();  // protect knT/vnT before next tile's writes
  }

  const int b = blockIdx.x >> 5;  // 32 row-groups per batch
  float* dbase = dots + (size_t)(b * 8 + h) * 4096;
#pragma unroll
  for (int fn = 0; fn < 4; ++fn) {
    int e = fn * 16 + m;
#pragma unroll
    for (int r = 0; r < 4; ++r) {
      int d = wave * 16 + q * 4 + r;
      atomicAdd(dbase + d * 64 + e, dacc[fn][r]);
    }
  }
}

// ---------------- fold dots into w_out (unchanged) ----------------
__global__ __launch_bounds__(256) void make_M(const float* __restrict__ dots,
                                              const float* __restrict__ wout,
                                              u16* __restrict__ Mbt) {
  __shared__ float dl[8][64];
  const int bh = blockIdx.x, b = bh >> 3, h = bh & 7;
  const int jg = blockIdx.y;
  const int c = threadIdx.x;
  for (int i = threadIdx.x; i < 512; i += 256)
    ((float*)dl)[i] = dots[(size_t)bh * 4096 + jg * 512 + i];
  __syncthreads();
  float accv[8];
#pragma unroll
  for (int jj = 0; jj < 8; ++jj) accv[jj] = 0.f;
  for (int e = 0; e < 64; ++e) {
    float w = wout[(h * 64 + e) * DIM + c];
#pragma unroll
    for (int jj = 0; jj < 8; ++jj) accv[jj] = fmaf(dl[jj][e], w, accv[jj]);
  }
  const float inv_n = 1.0f / (float)SEQ;
  u16* outp = Mbt + ((size_t)(b * 256 + c)) * 512 + h * 64 + jg * 8;
#pragma unroll
  for (int jj = 0; jj < 8; ++jj) outp[jj] = f2bf(accv[jj] * inv_n);
}

// ---------------- make_G (unchanged): Gt[b][c][k] = sum_j Mbt[b][c][j]*wqB[k][j] ----
__global__ __launch_bounds__(256) void make_G(const u16* __restrict__ Mbt,
                                              const u16* __restrict__ wqB,
                                              u16* __restrict__ Gt) {
  __shared__ alignas(16) u16 sA[128 * 64];
  __shared__ alignas(16) u16 sB[128 * 64];
  const int lane = threadIdx.x & 63, wave = threadIdx.x >> 6;
  const int row0 = blockIdx.x * 128, col0 = blockIdx.y * 128;
  const int b = blockIdx.z;
  f32x4 acc[4][4];
#pragma unroll
  for (int i = 0; i < 4; ++i)
#pragma unroll
    for (int j = 0; j < 4; ++j) acc[i][j] = (f32x4){0.f, 0.f, 0.f, 0.f};

  gemm_tile(Mbt + (size_t)b * 256 * 512, INNER, wqB, INNER, INNER, row0, col0, sA, sB, acc);

  u16* out = Gt + (size_t)b * 256 * 256;
  const int mr = (wave >> 1) * 64, nc = (wave & 1) * 64;
#pragma unroll
  for (int fm = 0; fm < 4; ++fm) {
    int rbase = row0 + mr + fm * 16 + (lane >> 4) * 4;
#pragma unroll
    for (int fn = 0; fn < 4; ++fn) {
      int col = col0 + nc + fn * 16 + (lane & 15);
#pragma unroll
      for (int r = 0; r < 4; ++r)
        out[(size_t)(rbase + r) * DIM + col] = f2bf(acc[fm][fn][r]);
    }
  }
}

// ---------------- gemm_out: out = x @ G[b] + bias — BARRIER-FREE, no LDS ----------------
// A and B frags both direct 16B loads (L2-hot); zero __syncthreads.
__global__ __launch_bounds__(256, 2) void gemm_out(const u16* __restrict__ A,
                                                   const u16* __restrict__ Gt,
                                                   const float* __restrict__ bias,
                                                   float* __restrict__ out) {
  const int tid = threadIdx.x, lane = tid & 63, wave = tid >> 6;
  const int m = lane & 15, q = lane >> 4;
  const int row0 = blockIdx.x * 128, col0 = blockIdx.y * 128;
  const int b = blockIdx.x >> 6;
  const u16* Bt = Gt + (size_t)b * 256 * 256;   // [256 cols][256 k]
  const int mr = (wave >> 1) * 64, nc = (wave & 1) * 64;
  const u16* ab = A  + (size_t)(row0 + mr + m) * DIM + q * 8;
  const u16* bb = Bt + (size_t)(col0 + nc + m) * DIM + q * 8;

  f32x4 acc[4][4];
#pragma unroll
  for (int i = 0; i < 4; ++i)
#pragma unroll
    for (int j = 0; j < 4; ++j) acc[i][j] = (f32x4){0.f, 0.f, 0.f, 0.f};

#pragma unroll
  for (int kx = 0; kx < 8; ++kx) {
    bf16x8 af[4], bfr[4];
#pragma unroll
    for (int f = 0; f < 4; ++f)
      af[f]  = *(const bf16x8*)(ab + (size_t)(f * 16) * DIM + kx * 32);
#pragma unroll
    for (int fn = 0; fn < 4; ++fn)
      bfr[fn] = *(const bf16x8*)(bb + (size_t)(fn * 16) * DIM + kx * 32);
#pragma unroll
    for (int fm = 0; fm < 4; ++fm)
#pragma unroll
      for (int fn = 0; fn < 4; ++fn)
        acc[fm][fn] = __builtin_amdgcn_mfma_f32_16x16x32_bf16(af[fm], bfr[fn], acc[fm][fn], 0, 0, 0);
  }

#pragma unroll
  for (int fm = 0; fm < 4; ++fm) {
    int rbase = row0 + mr + fm * 16 + q * 4;
#pragma unroll
    for (int fn = 0; fn < 4; ++fn) {
      int col = col0 + nc + fn * 16 + m;
      float bb2 = bias[col];
#pragma unroll
      for (int r = 0; r < 4; ++r)
        out[(size_t)(rbase + r) * DIM + col] = acc[fm][fn][r] + bb2;
    }
  }
}

// ---------------- launch ----------------
extern "C" void kernel_launch(void* const* d_in, const int* in_sizes, int n_in,
                              void* d_out, int out_size, void* d_ws, size_t ws_size,
                              hipStream_t stream) {
  const float* x     = (const float*)d_in[0];
  const float* w_qkv = (const float*)d_in[1];
  const float* w_out = (const float*)d_in[2];
  const float* b_out = (const float*)d_in[3];
  float* out = (float*)d_out;

  char* ws = (char*)d_ws;
  size_t off = 0;
  u16* xb    = (u16*)(ws + off); off += (size_t)ROWS * DIM * 2;          // 16.78 MB
  u16* wqB   = (u16*)(ws + off); off += (size_t)DIM * INNER * 2;         // 0.26 MB
  u16* wkvP  = (u16*)(ws + off); off += (size_t)HEADS * 128 * DIM * 2;   // 0.52 MB
  float* dots = (float*)(ws + off); off += (size_t)32 * 64 * 64 * 4;     // 0.52 MB
  u16* Mbt   = (u16*)(ws + off); off += (size_t)BATCH * 256 * 512 * 2;   // 1.05 MB
  u16* Gt    = (u16*)(ws + off); off += (size_t)BATCH * 256 * 256 * 2;   // 0.52 MB

  prep<<<9856, 256, 0, stream>>>(x, w_qkv, xb, wqB, wkvP, dots);
  gemm_kv_dots<<<dim3(ROWS / 256, HEADS), 256, 0, stream>>>(xb, wkvP, dots);
  make_M<<<dim3(32, 8), 256, 0, stream>>>(dots, w_out, Mbt);
  make_G<<<dim3(2, 2, BATCH), 256, 0, stream>>>(Mbt, wqB, Gt);
  gemm_out<<<dim3(ROWS / 128, 2), 256, 0, stream>>>(xb, Gt, b_out, out);
}